// Round 20
// baseline (742.015 us; speedup 1.0000x reference)
//
#include <hip/hip_runtime.h>

// Problem dims (fixed by the reference)
#define NN      2048
#define IN_DIM  784
#define NFEAT   100
#define NP      2000   // MW*MP
#define NS      30
#define OUTC    2100   // NFEAT + NP
#define NWIN    5      // 8-bit windows covering bits 2^-4 .. 2^-43
#define G4      4      // n-batch per block (tier A)
#define GB      4      // n-batch per block (tier B fallback)
#define CHUNK   64     // p per block

typedef double f64x4  __attribute__((ext_vector_type(4)));
typedef float  f32x4  __attribute__((ext_vector_type(4)));
typedef short  bf16x8 __attribute__((ext_vector_type(8)));

#define AS1 __attribute__((address_space(1)))
#define AS3 __attribute__((address_space(3)))

__device__ __forceinline__ void stage16(const void* g, void* l) {
    __builtin_amdgcn_global_load_lds((const AS1 unsigned int*)g,
                                     (AS3 unsigned int*)l, 16, 0, 0);
}

// Counted per-wave VMEM wait (T4, r19-proven): retire the 5 oldest ops (the
// B-stage for the next kt) while leaving the 8 acur loads in flight;
// sched_barrier keeps the following ds_read below the wait (rule #18).
#define VMWAIT8()                                                   \
    {                                                               \
        asm volatile("s_waitcnt vmcnt(8)" ::: "memory");            \
        __builtin_amdgcn_sched_barrier(0);                          \
    }

__device__ __forceinline__ f64x4 mfma_f64(double a, double b, f64x4 c) {
#if __has_builtin(__builtin_amdgcn_mfma_f64_16x16x4f64)
    return __builtin_amdgcn_mfma_f64_16x16x4f64(a, b, c, 0, 0, 0);
#else
    asm volatile("v_mfma_f64_16x16x4_f64 %0, %1, %2, %0"
                 : "+v"(c) : "v"(a), "v"(b));
    return c;
#endif
}

// ---------------------------------------------------------------------------
// Kernel 1: block-per-n feature layer + Bernoulli rate coding (f64).
// REVERTED to the r18 version: 2048 blocks x 128 threads. r19's K1G=4
// batching (512 blocks) starved TLP and cost ~28 us of total.
// ---------------------------------------------------------------------------
__global__ __launch_bounds__(128) void sbls_k1(
    const float* __restrict__ X, const float* __restrict__ W1,
    const float* __restrict__ B1, const float* __restrict__ U,
    float* __restrict__ out, unsigned* __restrict__ colmask)
{
    __shared__ float xs[IN_DIM];
    const int n = blockIdx.x;
    const int t = threadIdx.x;

    for (int k = t; k < IN_DIM; k += 128)
        xs[k] = X[(size_t)n * IN_DIM + k];
    __syncthreads();

    if (t >= NFEAT) return;
    const int f = t;

    double a0 = 0.0, a1 = 0.0, a2 = 0.0, a3 = 0.0;
    for (int k = 0; k < IN_DIM; k += 4) {   // 784 = 4*196 exact
        a0 += (double)xs[k + 0] * (double)W1[(k + 0) * NFEAT + f];
        a1 += (double)xs[k + 1] * (double)W1[(k + 1) * NFEAT + f];
        a2 += (double)xs[k + 2] * (double)W1[(k + 2) * NFEAT + f];
        a3 += (double)xs[k + 3] * (double)W1[(k + 3) * NFEAT + f];
    }
    double acc = (double)B1[f] + ((a0 + a1) + (a2 + a3));
    double z = 1.0 / (1.0 + exp(-acc / 3.0));

    unsigned m = 0;
    int cnt = 0;
    for (int s = 0; s < NS; ++s) {
        float u = U[(size_t)s * (NN * NFEAT) + (size_t)n * NFEAT + f];
        int sp = ((double)u < z) ? 1 : 0;
        m |= (unsigned)sp << s;
        cnt += sp;
    }
    colmask[n * NFEAT + f] = m;
    out[(size_t)n * OUTC + f] = (float)((double)cnt / 30.0);
}

// ---------------------------------------------------------------------------
// Slicer: W2 -> NWIN bf16 windows, transposed [w][p][f-pad128]. Exact.
// ---------------------------------------------------------------------------
__global__ __launch_bounds__(256) void sbls_slice(
    const float* __restrict__ W2, unsigned short* __restrict__ slt)
{
    int idx = blockIdx.x * blockDim.x + threadIdx.x;
    if (idx >= NP * 128) return;
    int f = idx & 127;
    int p = idx >> 7;

    double w = (f < NFEAT) ? (double)W2[(size_t)f * NP + p] : 0.0;
    double aw = fabs(w);
    double sg = (w < 0.0) ? -1.0 : 1.0;
    double r = aw;
    const double scale[NWIN] = {0x1p11, 0x1p19, 0x1p27, 0x1p35, 0x1p43};
#pragma unroll
    for (int j = 0; j < NWIN; ++j) {
        double t = floor(r * scale[j]);          // integer in [0,255], exact
        r = r - t / scale[j];                     // exact (power-of-2 grid)
        float v = (float)(sg * t / scale[j]);     // <=8 sig bits -> exact
        unsigned u = __builtin_bit_cast(unsigned, v);
        slt[((size_t)j * NP + p) * 128 + f] = (unsigned short)(u >> 16);
    }
}

// ---------------------------------------------------------------------------
// afrag builder (G4=4): one block per n-group. fid=(kt*4+n)*2+st (32 fids),
// afragG[((ng*32 + fid)*64 + L)*8] bf16.
// ---------------------------------------------------------------------------
__global__ __launch_bounds__(256) void sbls_afrag4(
    const unsigned* __restrict__ colmask, unsigned short* __restrict__ afragG)
{
    __shared__ unsigned smask[G4][NFEAT];
    const int ng = blockIdx.x;           // 0..511
    const int t  = threadIdx.x;

    for (int i = t; i < G4 * NFEAT; i += 256)
        smask[i / NFEAT][i % NFEAT] = colmask[ng * G4 * NFEAT + i];
    __syncthreads();

    for (int e = t; e < 32 * 64; e += 256) {
        int fid = e >> 6, L = e & 63;
        int st = fid & 1, n = (fid >> 1) & 3, kt = fid >> 3;
        int lgE = L >> 4, lmE = L & 15;
        int s = st * 16 + lmE;
        bf16x8 v;
#pragma unroll
        for (int j = 0; j < 8; ++j) {
            int f = kt * 32 + lgE * 8 + j;
            unsigned mv = (f < NFEAT) ? smask[n][f] : 0u;
            v[j] = (short)(((mv >> s) & 1u) ? 0x3F80 : 0);
        }
        *(bf16x8*)(afragG + ((size_t)ng * 32 + fid) * 64 * 8 + (size_t)L * 8) = v;
    }
}

// ---------------------------------------------------------------------------
// Kernel 2 (v20, tier A): r19 structure (counted vmcnt(8), barrier-free
// main loop) with __launch_bounds__(256, 4). Resource audit: LDS 40960 x 4
// = exactly the 160 KB pool; VGPR 84 quantizes to the 128-class -> 4
// blocks/CU possible. One extra resident block overlaps epilogue (VALU/f64
// LIF, matrix-pipe-idle) with another block's MFMA phase. Numerics
// byte-identical to rounds 6-19 (absmax 0.0). FETCH_SIZE = spill tripwire.
// ---------------------------------------------------------------------------
union ShA {
    unsigned short b[2][NWIN][64][32];  // 40960 B: [buf][w][p_local][f(swz)]
    double h[2][32][67];                // 34304 B (epilogue overlay, n-pairs)
};

__global__ __launch_bounds__(256, 4) void sbls_k2_ga(
    const unsigned short* __restrict__ slt,     // [NWIN][NP][128]
    const unsigned short* __restrict__ afragG,  // [512][32][64][8]
    const float*    __restrict__ B2,
    float*          __restrict__ out)
{
    __shared__ __align__(16) ShA sh;

    // XCD-aware remap (8 XCDs, 16384 blocks): XCD k owns ng in [k*64,(k+1)*64).
    const int lid  = blockIdx.y * 512 + blockIdx.x;   // 0..16383
    const int xcd  = lid & 7;
    const int idx  = lid >> 3;                        // 0..2047
    const int chunk = idx & 31;                       // 0..31
    const int ng    = xcd * 64 + (idx >> 5);          // 0..511

    const int t  = threadIdx.x;
    const int l  = t & 63;
    const int wv = t >> 6;
    const int lm = l & 15;
    const int lg = l >> 4;

    // --- stage-source geometry (writer role; r15-verified) ---
    const int plw = wv * 16 + (l >> 2);                 // p_local written
    const int pw  = chunk * CHUNK + plw;
    const int prw = (pw < NP) ? pw : (NP - 1);
    const int fgw = ((l & 3) - ((l >> 3) & 3)) & 3;     // fgrp fetched
    const unsigned short* sbase = slt + (size_t)prw * 128 + fgw * 8;

    const unsigned short* ag = afragG + (size_t)ng * 32 * 64 * 8;

    // --- MFMA-read geometry ---
    const int prd = wv * 16 + lm;                        // p_local read
    const int slot0 = (lm >> 1) & 3;

#define STAGE(buf, kt)                                                        \
    {                                                                         \
        _Pragma("unroll")                                                     \
        for (int w = 0; w < NWIN; ++w)                                        \
            stage16(sbase + (size_t)w * NP * 128 + (kt) * 32,                 \
                    &sh.b[buf][w][wv * 16][0]);                               \
    }

    f32x4 acc[3][2][G4];
#pragma unroll
    for (int wp = 0; wp < 3; ++wp)
#pragma unroll
        for (int st = 0; st < 2; ++st)
#pragma unroll
            for (int n = 0; n < G4; ++n)
                acc[wp][st][n] = (f32x4){0.f, 0.f, 0.f, 0.f};

    // Prologue: stage kt=0 (5 ops), preload A(kt=0) (8 ops), then retire
    // just the stages; the A-loads stay in flight until the compiler's own
    // wait before the first MFMA.
    STAGE(0, 0)
    bf16x8 acur[G4][2];
#pragma unroll
    for (int n = 0; n < G4; ++n)
#pragma unroll
        for (int st = 0; st < 2; ++st)
            acur[n][st] = *(const bf16x8*)(
                ag + ((size_t)((0 * G4 + n) * 2 + st) * 64 + l) * 8);
    VMWAIT8()

#pragma unroll
    for (int kt = 0; kt < 4; ++kt) {
        const int buf = kt & 1;
        if (kt < 3) STAGE(buf ^ 1, kt + 1)

        // B fragments from LDS (own band; swizzled slots, 2-way = free).
        bf16x8 b[NWIN];
#pragma unroll
        for (int w = 0; w < NWIN; ++w) {
            const int slot = (lg + slot0) & 3;
            b[w] = *(const bf16x8*)(&sh.b[buf][w][prd][slot * 8]);
        }

        __builtin_amdgcn_s_setprio(1);
#pragma unroll
        for (int w = 0; w < NWIN; ++w)
#pragma unroll
            for (int n = 0; n < G4; ++n)
#pragma unroll
                for (int st = 0; st < 2; ++st)
                    acc[w >> 1][st][n] = __builtin_amdgcn_mfma_f32_16x16x32_bf16(
                        acur[n][st], b[w], acc[w >> 1][st][n], 0, 0, 0);
        __builtin_amdgcn_s_setprio(0);

        // Direct acur reload (WAR on consumed regs; no extra live range),
        // then counted wait: retire stage(kt+1), keep acur(kt+1) in flight.
        if (kt < 3) {
#pragma unroll
            for (int n = 0; n < G4; ++n)
#pragma unroll
                for (int st = 0; st < 2; ++st)
                    acur[n][st] = *(const bf16x8*)(
                        ag + ((size_t)(((kt + 1) * G4 + n) * 2 + st) * 64 + l) * 8);
            VMWAIT8()
        }
    }
#undef STAGE

    // Epilogue: h overlays sh.b (cross-wave) -> real barriers from here on.
    __syncthreads();
#pragma unroll
    for (int np2 = 0; np2 < 2; ++np2) {
#pragma unroll
        for (int nn = 0; nn < 2; ++nn) {
            const int n = np2 * 2 + nn;
#pragma unroll
            for (int st = 0; st < 2; ++st)
#pragma unroll
                for (int r = 0; r < 4; ++r) {
                    double hv = (double)acc[0][st][n][r]
                              + (double)acc[1][st][n][r]
                              + (double)acc[2][st][n][r];
                    sh.h[nn][st * 16 + lg * 4 + r][wv * 16 + lm] = hv;
                }
        }
        __syncthreads();
        if (t < 128) {
            const int nn = t >> 6;
            const int pl = t & 63;
            const int pp = chunk * CHUNK + pl;
            if (pp < NP) {
                double b2d = (double)B2[pp];
                double mem = 0.0, spk = 0.0;
                int cnt = 0;
#pragma unroll
                for (int s = 0; s < NS; ++s) {
                    double hh = sh.h[nn][s][pl] + b2d;
                    mem = 0.9 * mem + hh - spk;
                    bool sp = mem > 1.0;
                    spk = sp ? 1.0 : 0.0;
                    cnt += sp;
                }
                out[(size_t)(ng * G4 + np2 * 2 + nn) * OUTC + NFEAT + pp] =
                    (float)((double)cnt / 30.0);
            }
        }
        if (np2 == 0) __syncthreads();   // LIF readers done before rewrite
    }
}

// ---------------------------------------------------------------------------
// Tier B fallback (round-12 structure, GB=4, (256,2)): proven 260 us.
// ---------------------------------------------------------------------------
__global__ __launch_bounds__(256, 2) void sbls_k2_bf16(
    const unsigned short* __restrict__ slt,
    const float*    __restrict__ B2,
    const unsigned* __restrict__ colmask,
    float*          __restrict__ out)
{
    __shared__ unsigned smask[GB][NFEAT];
    union ShU {
        unsigned short afrag[32][64][8];
        double h[GB][32][67];
    };
    __shared__ __align__(16) ShU shu;

    const int ng    = blockIdx.x;
    const int chunk = blockIdx.y;
    const int t  = threadIdx.x;
    const int l  = t & 63;
    const int wv = t >> 6;
    const int lm = l & 15;
    const int lg = l >> 4;

    for (int i = t; i < GB * NFEAT; i += 256)
        smask[i / NFEAT][i % NFEAT] = colmask[(ng * GB + i / NFEAT) * NFEAT + (i % NFEAT)];
    __syncthreads();

    for (int e = t; e < 32 * 64; e += 256) {
        int fid = e >> 6, L = e & 63;
        int st = fid & 1, n = (fid >> 1) & 3, kt = fid >> 3;
        int lgE = L >> 4, lmE = L & 15;
        int s = st * 16 + lmE;
        bf16x8 v;
#pragma unroll
        for (int j = 0; j < 8; ++j) {
            int f = kt * 32 + lgE * 8 + j;
            unsigned mv = (f < NFEAT) ? smask[n][f] : 0u;
            v[j] = (short)(((mv >> s) & 1u) ? 0x3F80 : 0);
        }
        *(bf16x8*)(&shu.afrag[fid][L][0]) = v;
    }
    __syncthreads();

    const int p = chunk * CHUNK + wv * 16 + lm;
    const int prow = (p < NP) ? p : (NP - 1);
    const unsigned short* bbase = slt + (size_t)prow * 128 + lg * 8;

    f32x4 acc[3][2][GB];
#pragma unroll
    for (int wp = 0; wp < 3; ++wp)
#pragma unroll
        for (int st = 0; st < 2; ++st)
#pragma unroll
            for (int n = 0; n < GB; ++n)
                acc[wp][st][n] = (f32x4){0.f, 0.f, 0.f, 0.f};

    bf16x8 bcur[NWIN], bnxt[NWIN];
#pragma unroll
    for (int w = 0; w < NWIN; ++w)
        bcur[w] = *(const bf16x8*)(bbase + (size_t)w * NP * 128);

#pragma unroll
    for (int kt = 0; kt < 4; ++kt) {
        bf16x8 a[GB][2];
#pragma unroll
        for (int n = 0; n < GB; ++n)
#pragma unroll
            for (int st = 0; st < 2; ++st)
                a[n][st] = *(const bf16x8*)(&shu.afrag[(kt * GB + n) * 2 + st][l][0]);

        if (kt < 3) {
#pragma unroll
            for (int w = 0; w < NWIN; ++w)
                bnxt[w] = *(const bf16x8*)(bbase + (size_t)w * NP * 128 + (kt + 1) * 32);
        }

#pragma unroll
        for (int w = 0; w < NWIN; ++w)
#pragma unroll
            for (int n = 0; n < GB; ++n)
#pragma unroll
                for (int st = 0; st < 2; ++st)
                    acc[w >> 1][st][n] = __builtin_amdgcn_mfma_f32_16x16x32_bf16(
                        a[n][st], bcur[w], acc[w >> 1][st][n], 0, 0, 0);

        if (kt < 3) {
#pragma unroll
            for (int w = 0; w < NWIN; ++w) bcur[w] = bnxt[w];
        }
    }

    __syncthreads();
#pragma unroll
    for (int n = 0; n < GB; ++n)
#pragma unroll
        for (int st = 0; st < 2; ++st)
#pragma unroll
            for (int r = 0; r < 4; ++r) {
                double hv = (double)acc[0][st][n][r]
                          + (double)acc[1][st][n][r]
                          + (double)acc[2][st][n][r];
                shu.h[n][st * 16 + lg * 4 + r][wv * 16 + lm] = hv;
            }
    __syncthreads();
    {
        const int nn = t >> 6;
        const int pl = t & 63;
        const int pp = chunk * CHUNK + pl;
        if (pp < NP) {
            double b2d = (double)B2[pp];
            double mem = 0.0, spk = 0.0;
            int cnt = 0;
#pragma unroll
            for (int s = 0; s < NS; ++s) {
                double hh = shu.h[nn][s][pl] + b2d;
                mem = 0.9 * mem + hh - spk;
                bool sp = mem > 1.0;
                spk = sp ? 1.0 : 0.0;
                cnt += sp;
            }
            out[(size_t)(ng * GB + nn) * OUTC + NFEAT + pp] = (float)((double)cnt / 30.0);
        }
    }
}

// ---------------------------------------------------------------------------
// Tier C fallback (round-5 f64 MFMA, probed layout).
// ---------------------------------------------------------------------------
__global__ __launch_bounds__(256, 2) void sbls_k2_f64(
    const float*    __restrict__ W2, const float* __restrict__ B2,
    const unsigned* __restrict__ colmask, float* __restrict__ out)
{
    __shared__ unsigned smask[NFEAT];
    __shared__ double h_lds[32][130];

    const int n     = blockIdx.x;
    const int chunk = blockIdx.y;
    const int l  = threadIdx.x & 63;
    const int wv = threadIdx.x >> 6;
    const int lm = l & 15;
    const int lg = l >> 4;

    if (threadIdx.x < NFEAT)
        smask[threadIdx.x] = colmask[n * NFEAT + threadIdx.x];

    f64x4 zero = (f64x4){0.0, 0.0, 0.0, 0.0};
    f64x4 d1 = mfma_f64((double)lm, 1.0, zero);
    f64x4 d2 = mfma_f64(1.0, (double)lm, zero);
    int srow[4], pcol[4];
#pragma unroll
    for (int r = 0; r < 4; ++r) {
        int a = (int)(d1[r] * 0.25);
        int b = (int)(d2[r] * 0.25);
        srow[r] = (a < 0) ? 0 : (a > 15 ? 15 : a);
        pcol[r] = (b < 0) ? 0 : (b > 15 ? 15 : b);
    }
    __syncthreads();

    f64x4 acc[2][4];
    int pclamp[4];
#pragma unroll
    for (int i = 0; i < 4; ++i) {
        int p = chunk * 256 + (wv * 4 + i) * 16 + lm;
        pclamp[i] = (p < NP) ? p : (NP - 1);
        acc[0][i] = zero; acc[1][i] = zero;
    }
    for (int kt = 0; kt < 25; ++kt) {
        unsigned mw = smask[kt * 4 + lg];
        double a0 = ((mw >> lm) & 1u) ? 1.0 : 0.0;
        double a1 = ((mw >> (lm + 16)) & 1u) ? 1.0 : 0.0;
        const float* wrow = W2 + (size_t)(kt * 4 + lg) * NP;
#pragma unroll
        for (int i = 0; i < 4; ++i) {
            double b = (double)wrow[pclamp[i]];
            acc[0][i] = mfma_f64(a0, b, acc[0][i]);
            acc[1][i] = mfma_f64(a1, b, acc[1][i]);
        }
    }
#pragma unroll
    for (int hp = 0; hp < 2; ++hp) {
        __syncthreads();
        if ((wv >> 1) == hp) {
#pragma unroll
            for (int i = 0; i < 4; ++i) {
                int tloc = (wv & 1) * 4 + i;
#pragma unroll
                for (int st = 0; st < 2; ++st)
#pragma unroll
                    for (int r = 0; r < 4; ++r)
                        h_lds[st * 16 + srow[r]][tloc * 16 + pcol[r]] = acc[st][i][r];
            }
        }
        __syncthreads();
        if (threadIdx.x < 128) {
            int p = chunk * 256 + hp * 128 + threadIdx.x;
            if (p < NP) {
                double b2d = (double)B2[p];
                double mem = 0.0, spk = 0.0;
                int cnt = 0;
#pragma unroll
                for (int s = 0; s < NS; ++s) {
                    double hh = h_lds[s][threadIdx.x] + b2d;
                    mem = 0.9 * mem + hh - spk;
                    bool sp = mem > 1.0;
                    spk = sp ? 1.0 : 0.0;
                    cnt += sp;
                }
                out[(size_t)n * OUTC + NFEAT + p] = (float)((double)cnt / 30.0);
            }
        }
    }
}

// ---------------------------------------------------------------------------
extern "C" void kernel_launch(void* const* d_in, const int* in_sizes, int n_in,
                              void* d_out, int out_size, void* d_ws, size_t ws_size,
                              hipStream_t stream) {
    const float* X  = (const float*)d_in[0];
    const float* W1 = (const float*)d_in[1];
    const float* B1 = (const float*)d_in[2];
    const float* W2 = (const float*)d_in[3];
    const float* B2 = (const float*)d_in[4];
    const float* U  = (const float*)d_in[5];
    float* out = (float*)d_out;

    unsigned* colmask = (unsigned*)d_ws;                      // 819,200 B
    const size_t SLT_OFF   = 1u << 20;                        // 1 MiB
    const size_t SLT_BYTES = (size_t)NWIN * NP * 128 * 2;     // 2,560,000 B
    const size_t AF_OFF    = 4u << 20;                        // 4 MiB
    const size_t AF_BYTES  = (size_t)(NN / G4) * 32 * 64 * 8 * 2; // 16,777,216 B
    unsigned short* slt    = (unsigned short*)((char*)d_ws + SLT_OFF);
    unsigned short* afragG = (unsigned short*)((char*)d_ws + AF_OFF);
    bool tierA = (ws_size >= AF_OFF + AF_BYTES);
    bool tierB = (ws_size >= SLT_OFF + SLT_BYTES);

    sbls_k1<<<NN, 128, 0, stream>>>(X, W1, B1, U, out, colmask);

    if (tierA) {
        sbls_slice<<<(NP * 128 + 255) / 256, 256, 0, stream>>>(W2, slt);
        sbls_afrag4<<<NN / G4, 256, 0, stream>>>(colmask, afragG);
        dim3 grid(512, 32);                                   // remapped in-kernel
        sbls_k2_ga<<<grid, 256, 0, stream>>>(slt, afragG, B2, out);
    } else if (tierB) {
        sbls_slice<<<(NP * 128 + 255) / 256, 256, 0, stream>>>(W2, slt);
        dim3 grid(NN / GB, (NP + CHUNK - 1) / CHUNK);
        sbls_k2_bf16<<<grid, 256, 0, stream>>>(slt, B2, colmask, out);
    } else {
        dim3 grid(NN, (NP + 255) / 256);
        sbls_k2_f64<<<grid, 256, 0, stream>>>(W2, B2, colmask, out);
    }
}

// Round 21
// 204.557 us; speedup vs baseline: 3.6274x; 3.6274x over previous
//
#include <hip/hip_runtime.h>

// Problem dims (fixed by the reference)
#define NN      2048
#define IN_DIM  784
#define NFEAT   100
#define NP      2000   // MW*MP
#define NS      30
#define OUTC    2100   // NFEAT + NP
#define NWIN    5      // 8-bit windows covering bits 2^-4 .. 2^-43
#define G4      4      // n-batch per block (tier A)
#define GB      4      // n-batch per block (tier B fallback)
#define CHUNK   64     // p per block

typedef double f64x4  __attribute__((ext_vector_type(4)));
typedef float  f32x4  __attribute__((ext_vector_type(4)));
typedef short  bf16x8 __attribute__((ext_vector_type(8)));

#define AS1 __attribute__((address_space(1)))
#define AS3 __attribute__((address_space(3)))

__device__ __forceinline__ void stage16(const void* g, void* l) {
    __builtin_amdgcn_global_load_lds((const AS1 unsigned int*)g,
                                     (AS3 unsigned int*)l, 16, 0, 0);
}

// Counted per-wave VMEM wait (T4, r19-proven): retire the 5 oldest ops (the
// B-stage for the next kt) while leaving the 8 acur loads in flight;
// sched_barrier keeps the following ds_read below the wait (rule #18).
#define VMWAIT8()                                                   \
    {                                                               \
        asm volatile("s_waitcnt vmcnt(8)" ::: "memory");            \
        __builtin_amdgcn_sched_barrier(0);                          \
    }

__device__ __forceinline__ f64x4 mfma_f64(double a, double b, f64x4 c) {
#if __has_builtin(__builtin_amdgcn_mfma_f64_16x16x4f64)
    return __builtin_amdgcn_mfma_f64_16x16x4f64(a, b, c, 0, 0, 0);
#else
    asm volatile("v_mfma_f64_16x16x4_f64 %0, %1, %2, %0"
                 : "+v"(c) : "v"(a), "v"(b));
    return c;
#endif
}

// ---------------------------------------------------------------------------
// Kernel 1: block-per-n feature layer + Bernoulli rate coding (f64).
// r18 version (2048 blocks x 128 threads) — proven fastest k1 config.
// ---------------------------------------------------------------------------
__global__ __launch_bounds__(128) void sbls_k1(
    const float* __restrict__ X, const float* __restrict__ W1,
    const float* __restrict__ B1, const float* __restrict__ U,
    float* __restrict__ out, unsigned* __restrict__ colmask)
{
    __shared__ float xs[IN_DIM];
    const int n = blockIdx.x;
    const int t = threadIdx.x;

    for (int k = t; k < IN_DIM; k += 128)
        xs[k] = X[(size_t)n * IN_DIM + k];
    __syncthreads();

    if (t >= NFEAT) return;
    const int f = t;

    double a0 = 0.0, a1 = 0.0, a2 = 0.0, a3 = 0.0;
    for (int k = 0; k < IN_DIM; k += 4) {   // 784 = 4*196 exact
        a0 += (double)xs[k + 0] * (double)W1[(k + 0) * NFEAT + f];
        a1 += (double)xs[k + 1] * (double)W1[(k + 1) * NFEAT + f];
        a2 += (double)xs[k + 2] * (double)W1[(k + 2) * NFEAT + f];
        a3 += (double)xs[k + 3] * (double)W1[(k + 3) * NFEAT + f];
    }
    double acc = (double)B1[f] + ((a0 + a1) + (a2 + a3));
    double z = 1.0 / (1.0 + exp(-acc / 3.0));

    unsigned m = 0;
    int cnt = 0;
    for (int s = 0; s < NS; ++s) {
        float u = U[(size_t)s * (NN * NFEAT) + (size_t)n * NFEAT + f];
        int sp = ((double)u < z) ? 1 : 0;
        m |= (unsigned)sp << s;
        cnt += sp;
    }
    colmask[n * NFEAT + f] = m;
    out[(size_t)n * OUTC + f] = (float)((double)cnt / 30.0);
}

// ---------------------------------------------------------------------------
// Slicer: W2 -> NWIN bf16 windows, transposed [w][p][f-pad128]. Exact.
// ---------------------------------------------------------------------------
__global__ __launch_bounds__(256) void sbls_slice(
    const float* __restrict__ W2, unsigned short* __restrict__ slt)
{
    int idx = blockIdx.x * blockDim.x + threadIdx.x;
    if (idx >= NP * 128) return;
    int f = idx & 127;
    int p = idx >> 7;

    double w = (f < NFEAT) ? (double)W2[(size_t)f * NP + p] : 0.0;
    double aw = fabs(w);
    double sg = (w < 0.0) ? -1.0 : 1.0;
    double r = aw;
    const double scale[NWIN] = {0x1p11, 0x1p19, 0x1p27, 0x1p35, 0x1p43};
#pragma unroll
    for (int j = 0; j < NWIN; ++j) {
        double t = floor(r * scale[j]);          // integer in [0,255], exact
        r = r - t / scale[j];                     // exact (power-of-2 grid)
        float v = (float)(sg * t / scale[j]);     // <=8 sig bits -> exact
        unsigned u = __builtin_bit_cast(unsigned, v);
        slt[((size_t)j * NP + p) * 128 + f] = (unsigned short)(u >> 16);
    }
}

// ---------------------------------------------------------------------------
// afrag builder (G4=4): one block per n-group. fid=(kt*4+n)*2+st (32 fids),
// afragG[((ng*32 + fid)*64 + L)*8] bf16.
// ---------------------------------------------------------------------------
__global__ __launch_bounds__(256) void sbls_afrag4(
    const unsigned* __restrict__ colmask, unsigned short* __restrict__ afragG)
{
    __shared__ unsigned smask[G4][NFEAT];
    const int ng = blockIdx.x;           // 0..511
    const int t  = threadIdx.x;

    for (int i = t; i < G4 * NFEAT; i += 256)
        smask[i / NFEAT][i % NFEAT] = colmask[ng * G4 * NFEAT + i];
    __syncthreads();

    for (int e = t; e < 32 * 64; e += 256) {
        int fid = e >> 6, L = e & 63;
        int st = fid & 1, n = (fid >> 1) & 3, kt = fid >> 3;
        int lgE = L >> 4, lmE = L & 15;
        int s = st * 16 + lmE;
        bf16x8 v;
#pragma unroll
        for (int j = 0; j < 8; ++j) {
            int f = kt * 32 + lgE * 8 + j;
            unsigned mv = (f < NFEAT) ? smask[n][f] : 0u;
            v[j] = (short)(((mv >> s) & 1u) ? 0x3F80 : 0);
        }
        *(bf16x8*)(afragG + ((size_t)ng * 32 + fid) * 64 * 8 + (size_t)L * 8) = v;
    }
}

// ---------------------------------------------------------------------------
// Kernel 2 (v21 = r19's proven best, tier A): G4 n-batch, LDS B-staging,
// barrier-free main loop with counted vmcnt(8), __launch_bounds__(256,3).
// r20 showed (256,4) is register-infeasible: the 96 f32 accumulators count
// against the unified 128-reg budget -> spill (FETCH 1.6 GB). At (256,3)
// the ~170-reg class fits (VGPR 84 arch + AGPR acc, no spill).
// Numerics byte-identical to rounds 6-19 (absmax 0.0).
// ---------------------------------------------------------------------------
union ShA {
    unsigned short b[2][NWIN][64][32];  // 40960 B: [buf][w][p_local][f(swz)]
    double h[2][32][67];                // 34304 B (epilogue overlay, n-pairs)
};

__global__ __launch_bounds__(256, 3) void sbls_k2_ga(
    const unsigned short* __restrict__ slt,     // [NWIN][NP][128]
    const unsigned short* __restrict__ afragG,  // [512][32][64][8]
    const float*    __restrict__ B2,
    float*          __restrict__ out)
{
    __shared__ __align__(16) ShA sh;

    // XCD-aware remap (8 XCDs, 16384 blocks): XCD k owns ng in [k*64,(k+1)*64).
    const int lid  = blockIdx.y * 512 + blockIdx.x;   // 0..16383
    const int xcd  = lid & 7;
    const int idx  = lid >> 3;                        // 0..2047
    const int chunk = idx & 31;                       // 0..31
    const int ng    = xcd * 64 + (idx >> 5);          // 0..511

    const int t  = threadIdx.x;
    const int l  = t & 63;
    const int wv = t >> 6;
    const int lm = l & 15;
    const int lg = l >> 4;

    // --- stage-source geometry (writer role; r15-verified) ---
    const int plw = wv * 16 + (l >> 2);                 // p_local written
    const int pw  = chunk * CHUNK + plw;
    const int prw = (pw < NP) ? pw : (NP - 1);
    const int fgw = ((l & 3) - ((l >> 3) & 3)) & 3;     // fgrp fetched
    const unsigned short* sbase = slt + (size_t)prw * 128 + fgw * 8;

    const unsigned short* ag = afragG + (size_t)ng * 32 * 64 * 8;

    // --- MFMA-read geometry ---
    const int prd = wv * 16 + lm;                        // p_local read
    const int slot0 = (lm >> 1) & 3;

#define STAGE(buf, kt)                                                        \
    {                                                                         \
        _Pragma("unroll")                                                     \
        for (int w = 0; w < NWIN; ++w)                                        \
            stage16(sbase + (size_t)w * NP * 128 + (kt) * 32,                 \
                    &sh.b[buf][w][wv * 16][0]);                               \
    }

    f32x4 acc[3][2][G4];
#pragma unroll
    for (int wp = 0; wp < 3; ++wp)
#pragma unroll
        for (int st = 0; st < 2; ++st)
#pragma unroll
            for (int n = 0; n < G4; ++n)
                acc[wp][st][n] = (f32x4){0.f, 0.f, 0.f, 0.f};

    // Prologue: stage kt=0 (5 ops), preload A(kt=0) (8 ops), then retire
    // just the stages; the A-loads stay in flight until the compiler's own
    // wait before the first MFMA.
    STAGE(0, 0)
    bf16x8 acur[G4][2];
#pragma unroll
    for (int n = 0; n < G4; ++n)
#pragma unroll
        for (int st = 0; st < 2; ++st)
            acur[n][st] = *(const bf16x8*)(
                ag + ((size_t)((0 * G4 + n) * 2 + st) * 64 + l) * 8);
    VMWAIT8()

#pragma unroll
    for (int kt = 0; kt < 4; ++kt) {
        const int buf = kt & 1;
        if (kt < 3) STAGE(buf ^ 1, kt + 1)

        // B fragments from LDS (own band; swizzled slots, 2-way = free).
        bf16x8 b[NWIN];
#pragma unroll
        for (int w = 0; w < NWIN; ++w) {
            const int slot = (lg + slot0) & 3;
            b[w] = *(const bf16x8*)(&sh.b[buf][w][prd][slot * 8]);
        }

        __builtin_amdgcn_s_setprio(1);
#pragma unroll
        for (int w = 0; w < NWIN; ++w)
#pragma unroll
            for (int n = 0; n < G4; ++n)
#pragma unroll
                for (int st = 0; st < 2; ++st)
                    acc[w >> 1][st][n] = __builtin_amdgcn_mfma_f32_16x16x32_bf16(
                        acur[n][st], b[w], acc[w >> 1][st][n], 0, 0, 0);
        __builtin_amdgcn_s_setprio(0);

        // Direct acur reload (WAR on consumed regs; no extra live range),
        // then counted wait: retire stage(kt+1), keep acur(kt+1) in flight.
        if (kt < 3) {
#pragma unroll
            for (int n = 0; n < G4; ++n)
#pragma unroll
                for (int st = 0; st < 2; ++st)
                    acur[n][st] = *(const bf16x8*)(
                        ag + ((size_t)(((kt + 1) * G4 + n) * 2 + st) * 64 + l) * 8);
            VMWAIT8()
        }
    }
#undef STAGE

    // Epilogue: h overlays sh.b (cross-wave) -> real barriers from here on.
    __syncthreads();
#pragma unroll
    for (int np2 = 0; np2 < 2; ++np2) {
#pragma unroll
        for (int nn = 0; nn < 2; ++nn) {
            const int n = np2 * 2 + nn;
#pragma unroll
            for (int st = 0; st < 2; ++st)
#pragma unroll
                for (int r = 0; r < 4; ++r) {
                    double hv = (double)acc[0][st][n][r]
                              + (double)acc[1][st][n][r]
                              + (double)acc[2][st][n][r];
                    sh.h[nn][st * 16 + lg * 4 + r][wv * 16 + lm] = hv;
                }
        }
        __syncthreads();
        if (t < 128) {
            const int nn = t >> 6;
            const int pl = t & 63;
            const int pp = chunk * CHUNK + pl;
            if (pp < NP) {
                double b2d = (double)B2[pp];
                double mem = 0.0, spk = 0.0;
                int cnt = 0;
#pragma unroll
                for (int s = 0; s < NS; ++s) {
                    double hh = sh.h[nn][s][pl] + b2d;
                    mem = 0.9 * mem + hh - spk;
                    bool sp = mem > 1.0;
                    spk = sp ? 1.0 : 0.0;
                    cnt += sp;
                }
                out[(size_t)(ng * G4 + np2 * 2 + nn) * OUTC + NFEAT + pp] =
                    (float)((double)cnt / 30.0);
            }
        }
        if (np2 == 0) __syncthreads();   // LIF readers done before rewrite
    }
}

// ---------------------------------------------------------------------------
// Tier B fallback (round-12 structure, GB=4, (256,2)): proven 260 us.
// ---------------------------------------------------------------------------
__global__ __launch_bounds__(256, 2) void sbls_k2_bf16(
    const unsigned short* __restrict__ slt,
    const float*    __restrict__ B2,
    const unsigned* __restrict__ colmask,
    float*          __restrict__ out)
{
    __shared__ unsigned smask[GB][NFEAT];
    union ShU {
        unsigned short afrag[32][64][8];
        double h[GB][32][67];
    };
    __shared__ __align__(16) ShU shu;

    const int ng    = blockIdx.x;
    const int chunk = blockIdx.y;
    const int t  = threadIdx.x;
    const int l  = t & 63;
    const int wv = t >> 6;
    const int lm = l & 15;
    const int lg = l >> 4;

    for (int i = t; i < GB * NFEAT; i += 256)
        smask[i / NFEAT][i % NFEAT] = colmask[(ng * GB + i / NFEAT) * NFEAT + (i % NFEAT)];
    __syncthreads();

    for (int e = t; e < 32 * 64; e += 256) {
        int fid = e >> 6, L = e & 63;
        int st = fid & 1, n = (fid >> 1) & 3, kt = fid >> 3;
        int lgE = L >> 4, lmE = L & 15;
        int s = st * 16 + lmE;
        bf16x8 v;
#pragma unroll
        for (int j = 0; j < 8; ++j) {
            int f = kt * 32 + lgE * 8 + j;
            unsigned mv = (f < NFEAT) ? smask[n][f] : 0u;
            v[j] = (short)(((mv >> s) & 1u) ? 0x3F80 : 0);
        }
        *(bf16x8*)(&shu.afrag[fid][L][0]) = v;
    }
    __syncthreads();

    const int p = chunk * CHUNK + wv * 16 + lm;
    const int prow = (p < NP) ? p : (NP - 1);
    const unsigned short* bbase = slt + (size_t)prow * 128 + lg * 8;

    f32x4 acc[3][2][GB];
#pragma unroll
    for (int wp = 0; wp < 3; ++wp)
#pragma unroll
        for (int st = 0; st < 2; ++st)
#pragma unroll
            for (int n = 0; n < GB; ++n)
                acc[wp][st][n] = (f32x4){0.f, 0.f, 0.f, 0.f};

    bf16x8 bcur[NWIN], bnxt[NWIN];
#pragma unroll
    for (int w = 0; w < NWIN; ++w)
        bcur[w] = *(const bf16x8*)(bbase + (size_t)w * NP * 128);

#pragma unroll
    for (int kt = 0; kt < 4; ++kt) {
        bf16x8 a[GB][2];
#pragma unroll
        for (int n = 0; n < GB; ++n)
#pragma unroll
            for (int st = 0; st < 2; ++st)
                a[n][st] = *(const bf16x8*)(&shu.afrag[(kt * GB + n) * 2 + st][l][0]);

        if (kt < 3) {
#pragma unroll
            for (int w = 0; w < NWIN; ++w)
                bnxt[w] = *(const bf16x8*)(bbase + (size_t)w * NP * 128 + (kt + 1) * 32);
        }

#pragma unroll
        for (int w = 0; w < NWIN; ++w)
#pragma unroll
            for (int n = 0; n < GB; ++n)
#pragma unroll
                for (int st = 0; st < 2; ++st)
                    acc[w >> 1][st][n] = __builtin_amdgcn_mfma_f32_16x16x32_bf16(
                        a[n][st], bcur[w], acc[w >> 1][st][n], 0, 0, 0);

        if (kt < 3) {
#pragma unroll
            for (int w = 0; w < NWIN; ++w) bcur[w] = bnxt[w];
        }
    }

    __syncthreads();
#pragma unroll
    for (int n = 0; n < GB; ++n)
#pragma unroll
        for (int st = 0; st < 2; ++st)
#pragma unroll
            for (int r = 0; r < 4; ++r) {
                double hv = (double)acc[0][st][n][r]
                          + (double)acc[1][st][n][r]
                          + (double)acc[2][st][n][r];
                shu.h[n][st * 16 + lg * 4 + r][wv * 16 + lm] = hv;
            }
    __syncthreads();
    {
        const int nn = t >> 6;
        const int pl = t & 63;
        const int pp = chunk * CHUNK + pl;
        if (pp < NP) {
            double b2d = (double)B2[pp];
            double mem = 0.0, spk = 0.0;
            int cnt = 0;
#pragma unroll
            for (int s = 0; s < NS; ++s) {
                double hh = shu.h[nn][s][pl] + b2d;
                mem = 0.9 * mem + hh - spk;
                bool sp = mem > 1.0;
                spk = sp ? 1.0 : 0.0;
                cnt += sp;
            }
            out[(size_t)(ng * GB + nn) * OUTC + NFEAT + pp] = (float)((double)cnt / 30.0);
        }
    }
}

// ---------------------------------------------------------------------------
// Tier C fallback (round-5 f64 MFMA, probed layout).
// ---------------------------------------------------------------------------
__global__ __launch_bounds__(256, 2) void sbls_k2_f64(
    const float*    __restrict__ W2, const float* __restrict__ B2,
    const unsigned* __restrict__ colmask, float* __restrict__ out)
{
    __shared__ unsigned smask[NFEAT];
    __shared__ double h_lds[32][130];

    const int n     = blockIdx.x;
    const int chunk = blockIdx.y;
    const int l  = threadIdx.x & 63;
    const int wv = threadIdx.x >> 6;
    const int lm = l & 15;
    const int lg = l >> 4;

    if (threadIdx.x < NFEAT)
        smask[threadIdx.x] = colmask[n * NFEAT + threadIdx.x];

    f64x4 zero = (f64x4){0.0, 0.0, 0.0, 0.0};
    f64x4 d1 = mfma_f64((double)lm, 1.0, zero);
    f64x4 d2 = mfma_f64(1.0, (double)lm, zero);
    int srow[4], pcol[4];
#pragma unroll
    for (int r = 0; r < 4; ++r) {
        int a = (int)(d1[r] * 0.25);
        int b = (int)(d2[r] * 0.25);
        srow[r] = (a < 0) ? 0 : (a > 15 ? 15 : a);
        pcol[r] = (b < 0) ? 0 : (b > 15 ? 15 : b);
    }
    __syncthreads();

    f64x4 acc[2][4];
    int pclamp[4];
#pragma unroll
    for (int i = 0; i < 4; ++i) {
        int p = chunk * 256 + (wv * 4 + i) * 16 + lm;
        pclamp[i] = (p < NP) ? p : (NP - 1);
        acc[0][i] = zero; acc[1][i] = zero;
    }
    for (int kt = 0; kt < 25; ++kt) {
        unsigned mw = smask[kt * 4 + lg];
        double a0 = ((mw >> lm) & 1u) ? 1.0 : 0.0;
        double a1 = ((mw >> (lm + 16)) & 1u) ? 1.0 : 0.0;
        const float* wrow = W2 + (size_t)(kt * 4 + lg) * NP;
#pragma unroll
        for (int i = 0; i < 4; ++i) {
            double b = (double)wrow[pclamp[i]];
            acc[0][i] = mfma_f64(a0, b, acc[0][i]);
            acc[1][i] = mfma_f64(a1, b, acc[1][i]);
        }
    }
#pragma unroll
    for (int hp = 0; hp < 2; ++hp) {
        __syncthreads();
        if ((wv >> 1) == hp) {
#pragma unroll
            for (int i = 0; i < 4; ++i) {
                int tloc = (wv & 1) * 4 + i;
#pragma unroll
                for (int st = 0; st < 2; ++st)
#pragma unroll
                    for (int r = 0; r < 4; ++r)
                        h_lds[st * 16 + srow[r]][tloc * 16 + pcol[r]] = acc[st][i][r];
            }
        }
        __syncthreads();
        if (threadIdx.x < 128) {
            int p = chunk * 256 + hp * 128 + threadIdx.x;
            if (p < NP) {
                double b2d = (double)B2[p];
                double mem = 0.0, spk = 0.0;
                int cnt = 0;
#pragma unroll
                for (int s = 0; s < NS; ++s) {
                    double hh = h_lds[s][threadIdx.x] + b2d;
                    mem = 0.9 * mem + hh - spk;
                    bool sp = mem > 1.0;
                    spk = sp ? 1.0 : 0.0;
                    cnt += sp;
                }
                out[(size_t)n * OUTC + NFEAT + p] = (float)((double)cnt / 30.0);
            }
        }
    }
}

// ---------------------------------------------------------------------------
extern "C" void kernel_launch(void* const* d_in, const int* in_sizes, int n_in,
                              void* d_out, int out_size, void* d_ws, size_t ws_size,
                              hipStream_t stream) {
    const float* X  = (const float*)d_in[0];
    const float* W1 = (const float*)d_in[1];
    const float* B1 = (const float*)d_in[2];
    const float* W2 = (const float*)d_in[3];
    const float* B2 = (const float*)d_in[4];
    const float* U  = (const float*)d_in[5];
    float* out = (float*)d_out;

    unsigned* colmask = (unsigned*)d_ws;                      // 819,200 B
    const size_t SLT_OFF   = 1u << 20;                        // 1 MiB
    const size_t SLT_BYTES = (size_t)NWIN * NP * 128 * 2;     // 2,560,000 B
    const size_t AF_OFF    = 4u << 20;                        // 4 MiB
    const size_t AF_BYTES  = (size_t)(NN / G4) * 32 * 64 * 8 * 2; // 16,777,216 B
    unsigned short* slt    = (unsigned short*)((char*)d_ws + SLT_OFF);
    unsigned short* afragG = (unsigned short*)((char*)d_ws + AF_OFF);
    bool tierA = (ws_size >= AF_OFF + AF_BYTES);
    bool tierB = (ws_size >= SLT_OFF + SLT_BYTES);

    sbls_k1<<<NN, 128, 0, stream>>>(X, W1, B1, U, out, colmask);

    if (tierA) {
        sbls_slice<<<(NP * 128 + 255) / 256, 256, 0, stream>>>(W2, slt);
        sbls_afrag4<<<NN / G4, 256, 0, stream>>>(colmask, afragG);
        dim3 grid(512, 32);                                   // remapped in-kernel
        sbls_k2_ga<<<grid, 256, 0, stream>>>(slt, afragG, B2, out);
    } else if (tierB) {
        sbls_slice<<<(NP * 128 + 255) / 256, 256, 0, stream>>>(W2, slt);
        dim3 grid(NN / GB, (NP + CHUNK - 1) / CHUNK);
        sbls_k2_bf16<<<grid, 256, 0, stream>>>(slt, B2, colmask, out);
    } else {
        dim3 grid(NN, (NP + 255) / 256);
        sbls_k2_f64<<<grid, 256, 0, stream>>>(W2, B2, colmask, out);
    }
}

// Round 22
// 203.083 us; speedup vs baseline: 3.6538x; 1.0073x over previous
//
#include <hip/hip_runtime.h>

// Problem dims (fixed by the reference)
#define NN      2048
#define IN_DIM  784
#define NFEAT   100
#define NP      2000   // MW*MP
#define NS      30
#define OUTC    2100   // NFEAT + NP
#define NWIN    5      // 8-bit windows covering bits 2^-4 .. 2^-43
#define G4      4      // n-batch per block (tier A)
#define GB      4      // n-batch per block (tier B fallback)
#define CHUNK   64     // p per block
#define K1B     2      // n per block in kernel 1

typedef double f64x4  __attribute__((ext_vector_type(4)));
typedef float  f32x4  __attribute__((ext_vector_type(4)));
typedef short  bf16x8 __attribute__((ext_vector_type(8)));

#define AS1 __attribute__((address_space(1)))
#define AS3 __attribute__((address_space(3)))

__device__ __forceinline__ void stage16(const void* g, void* l) {
    __builtin_amdgcn_global_load_lds((const AS1 unsigned int*)g,
                                     (AS3 unsigned int*)l, 16, 0, 0);
}

// Counted per-wave VMEM wait (T4, r19-proven): retire the 5 oldest ops (the
// B-stage for the next kt) while leaving the 8 acur loads in flight;
// sched_barrier keeps the following ds_read below the wait (rule #18).
#define VMWAIT8()                                                   \
    {                                                               \
        asm volatile("s_waitcnt vmcnt(8)" ::: "memory");            \
        __builtin_amdgcn_sched_barrier(0);                          \
    }

__device__ __forceinline__ f64x4 mfma_f64(double a, double b, f64x4 c) {
#if __has_builtin(__builtin_amdgcn_mfma_f64_16x16x4f64)
    return __builtin_amdgcn_mfma_f64_16x16x4f64(a, b, c, 0, 0, 0);
#else
    asm volatile("v_mfma_f64_16x16x4_f64 %0, %1, %2, %0"
                 : "+v"(c) : "v"(a), "v"(b));
    return c;
#endif
}

// ---------------------------------------------------------------------------
// Kernel 1 (v22): 2-n-per-block feature layer + Bernoulli rate coding.
// r21's k1 was L2-BW-bound on W1 re-reads (2048 blocks x 313 KB = 642 MB
// ~ 19 us at L2 BW). 2 n's share each W1[k][f] load (second wave L1-hits)
// -> W1 traffic halves; 1024 blocks x 256 thr keeps 4 blocks/CU TLP.
// Per-(n,f) f64 arithmetic ORDER byte-identical to the r18/r21 k1 (passed
// with absmax 0.0): a0..a3 over k mod 4, (a0+a1)+(a2+a3), then +B1.
// ---------------------------------------------------------------------------
__global__ __launch_bounds__(256) void sbls_k1(
    const float* __restrict__ X, const float* __restrict__ W1,
    const float* __restrict__ B1, const float* __restrict__ U,
    float* __restrict__ out, unsigned* __restrict__ colmask)
{
    __shared__ float xs[K1B][IN_DIM];
    const int n0 = blockIdx.x * K1B;
    const int t  = threadIdx.x;

    for (int i = t; i < K1B * IN_DIM; i += 256) {
        int nn = i / IN_DIM, k = i - nn * IN_DIM;
        xs[nn][k] = X[(size_t)(n0 + nn) * IN_DIM + k];
    }
    __syncthreads();

    const int nn = t >> 7;      // 0..1
    const int f  = t & 127;
    if (f >= NFEAT) return;
    const int n = n0 + nn;

    double a0 = 0.0, a1 = 0.0, a2 = 0.0, a3 = 0.0;
    for (int k = 0; k < IN_DIM; k += 4) {   // 784 = 4*196 exact
        a0 += (double)xs[nn][k + 0] * (double)W1[(k + 0) * NFEAT + f];
        a1 += (double)xs[nn][k + 1] * (double)W1[(k + 1) * NFEAT + f];
        a2 += (double)xs[nn][k + 2] * (double)W1[(k + 2) * NFEAT + f];
        a3 += (double)xs[nn][k + 3] * (double)W1[(k + 3) * NFEAT + f];
    }
    double acc = (double)B1[f] + ((a0 + a1) + (a2 + a3));
    double z = 1.0 / (1.0 + exp(-acc / 3.0));

    unsigned m = 0;
    int cnt = 0;
    for (int s = 0; s < NS; ++s) {
        float u = U[(size_t)s * (NN * NFEAT) + (size_t)n * NFEAT + f];
        int sp = ((double)u < z) ? 1 : 0;
        m |= (unsigned)sp << s;
        cnt += sp;
    }
    colmask[n * NFEAT + f] = m;
    out[(size_t)n * OUTC + f] = (float)((double)cnt / 30.0);
}

// ---------------------------------------------------------------------------
// Fused aux kernel (tier A): blocks 0..999 run the slicer role (exact NWIN
// bf16 windows, byte-identical output to sbls_slice); blocks 1000..1511 run
// the afrag-builder role (byte-identical to sbls_afrag4). Removes one
// launch gap and overlaps the two small kernels.
// ---------------------------------------------------------------------------
__global__ __launch_bounds__(256) void sbls_aux(
    const float*    __restrict__ W2,      unsigned short* __restrict__ slt,
    const unsigned* __restrict__ colmask, unsigned short* __restrict__ afragG)
{
    __shared__ unsigned smask[G4][NFEAT];
    const int b = blockIdx.x;
    const int t = threadIdx.x;

    if (b < 1000) {
        // ---- slice role: 1000*256 = NP*128 exactly ----
        int idx = b * 256 + t;
        int f = idx & 127;
        int p = idx >> 7;

        double w = (f < NFEAT) ? (double)W2[(size_t)f * NP + p] : 0.0;
        double aw = fabs(w);
        double sg = (w < 0.0) ? -1.0 : 1.0;
        double r = aw;
        const double scale[NWIN] = {0x1p11, 0x1p19, 0x1p27, 0x1p35, 0x1p43};
#pragma unroll
        for (int j = 0; j < NWIN; ++j) {
            double tt = floor(r * scale[j]);          // integer in [0,255]
            r = r - tt / scale[j];                     // exact
            float v = (float)(sg * tt / scale[j]);     // <=8 sig bits exact
            unsigned u = __builtin_bit_cast(unsigned, v);
            slt[((size_t)j * NP + p) * 128 + f] = (unsigned short)(u >> 16);
        }
    } else {
        // ---- afrag role ----
        const int ng = b - 1000;   // 0..511
        for (int i = t; i < G4 * NFEAT; i += 256)
            smask[i / NFEAT][i % NFEAT] = colmask[ng * G4 * NFEAT + i];
        __syncthreads();

        for (int e = t; e < 32 * 64; e += 256) {
            int fid = e >> 6, L = e & 63;
            int st = fid & 1, n = (fid >> 1) & 3, kt = fid >> 3;
            int lgE = L >> 4, lmE = L & 15;
            int s = st * 16 + lmE;
            bf16x8 v;
#pragma unroll
            for (int j = 0; j < 8; ++j) {
                int f = kt * 32 + lgE * 8 + j;
                unsigned mv = (f < NFEAT) ? smask[n][f] : 0u;
                v[j] = (short)(((mv >> s) & 1u) ? 0x3F80 : 0);
            }
            *(bf16x8*)(afragG + ((size_t)ng * 32 + fid) * 64 * 8 + (size_t)L * 8) = v;
        }
    }
}

// ---------------------------------------------------------------------------
// Standalone slicer (tier B fallback only).
// ---------------------------------------------------------------------------
__global__ __launch_bounds__(256) void sbls_slice(
    const float* __restrict__ W2, unsigned short* __restrict__ slt)
{
    int idx = blockIdx.x * blockDim.x + threadIdx.x;
    if (idx >= NP * 128) return;
    int f = idx & 127;
    int p = idx >> 7;

    double w = (f < NFEAT) ? (double)W2[(size_t)f * NP + p] : 0.0;
    double aw = fabs(w);
    double sg = (w < 0.0) ? -1.0 : 1.0;
    double r = aw;
    const double scale[NWIN] = {0x1p11, 0x1p19, 0x1p27, 0x1p35, 0x1p43};
#pragma unroll
    for (int j = 0; j < NWIN; ++j) {
        double t = floor(r * scale[j]);
        r = r - t / scale[j];
        float v = (float)(sg * t / scale[j]);
        unsigned u = __builtin_bit_cast(unsigned, v);
        slt[((size_t)j * NP + p) * 128 + f] = (unsigned short)(u >> 16);
    }
}

// ---------------------------------------------------------------------------
// Kernel 2 (tier A) — byte-identical to the r21-proven best (177.6 us):
// G4 n-batch, LDS B-staging via global_load_lds, barrier-free main loop with
// counted vmcnt(8), (256,3). r20 proved (256,4) is register-infeasible (96
// f32 accs count against the unified budget -> spill).
// Numerics byte-identical to rounds 6-21 (absmax 0.0).
// ---------------------------------------------------------------------------
union ShA {
    unsigned short b[2][NWIN][64][32];  // 40960 B: [buf][w][p_local][f(swz)]
    double h[2][32][67];                // 34304 B (epilogue overlay, n-pairs)
};

__global__ __launch_bounds__(256, 3) void sbls_k2_ga(
    const unsigned short* __restrict__ slt,     // [NWIN][NP][128]
    const unsigned short* __restrict__ afragG,  // [512][32][64][8]
    const float*    __restrict__ B2,
    float*          __restrict__ out)
{
    __shared__ __align__(16) ShA sh;

    // XCD-aware remap (8 XCDs, 16384 blocks): XCD k owns ng in [k*64,(k+1)*64).
    const int lid  = blockIdx.y * 512 + blockIdx.x;   // 0..16383
    const int xcd  = lid & 7;
    const int idx  = lid >> 3;                        // 0..2047
    const int chunk = idx & 31;                       // 0..31
    const int ng    = xcd * 64 + (idx >> 5);          // 0..511

    const int t  = threadIdx.x;
    const int l  = t & 63;
    const int wv = t >> 6;
    const int lm = l & 15;
    const int lg = l >> 4;

    // --- stage-source geometry (writer role; r15-verified) ---
    const int plw = wv * 16 + (l >> 2);                 // p_local written
    const int pw  = chunk * CHUNK + plw;
    const int prw = (pw < NP) ? pw : (NP - 1);
    const int fgw = ((l & 3) - ((l >> 3) & 3)) & 3;     // fgrp fetched
    const unsigned short* sbase = slt + (size_t)prw * 128 + fgw * 8;

    const unsigned short* ag = afragG + (size_t)ng * 32 * 64 * 8;

    // --- MFMA-read geometry ---
    const int prd = wv * 16 + lm;                        // p_local read
    const int slot0 = (lm >> 1) & 3;

#define STAGE(buf, kt)                                                        \
    {                                                                         \
        _Pragma("unroll")                                                     \
        for (int w = 0; w < NWIN; ++w)                                        \
            stage16(sbase + (size_t)w * NP * 128 + (kt) * 32,                 \
                    &sh.b[buf][w][wv * 16][0]);                               \
    }

    f32x4 acc[3][2][G4];
#pragma unroll
    for (int wp = 0; wp < 3; ++wp)
#pragma unroll
        for (int st = 0; st < 2; ++st)
#pragma unroll
            for (int n = 0; n < G4; ++n)
                acc[wp][st][n] = (f32x4){0.f, 0.f, 0.f, 0.f};

    // Prologue: stage kt=0 (5 ops), preload A(kt=0) (8 ops), then retire
    // just the stages; the A-loads stay in flight until the compiler's own
    // wait before the first MFMA.
    STAGE(0, 0)
    bf16x8 acur[G4][2];
#pragma unroll
    for (int n = 0; n < G4; ++n)
#pragma unroll
        for (int st = 0; st < 2; ++st)
            acur[n][st] = *(const bf16x8*)(
                ag + ((size_t)((0 * G4 + n) * 2 + st) * 64 + l) * 8);
    VMWAIT8()

#pragma unroll
    for (int kt = 0; kt < 4; ++kt) {
        const int buf = kt & 1;
        if (kt < 3) STAGE(buf ^ 1, kt + 1)

        // B fragments from LDS (own band; swizzled slots, 2-way = free).
        bf16x8 b[NWIN];
#pragma unroll
        for (int w = 0; w < NWIN; ++w) {
            const int slot = (lg + slot0) & 3;
            b[w] = *(const bf16x8*)(&sh.b[buf][w][prd][slot * 8]);
        }

        __builtin_amdgcn_s_setprio(1);
#pragma unroll
        for (int w = 0; w < NWIN; ++w)
#pragma unroll
            for (int n = 0; n < G4; ++n)
#pragma unroll
                for (int st = 0; st < 2; ++st)
                    acc[w >> 1][st][n] = __builtin_amdgcn_mfma_f32_16x16x32_bf16(
                        acur[n][st], b[w], acc[w >> 1][st][n], 0, 0, 0);
        __builtin_amdgcn_s_setprio(0);

        // Direct acur reload (WAR on consumed regs; no extra live range),
        // then counted wait: retire stage(kt+1), keep acur(kt+1) in flight.
        if (kt < 3) {
#pragma unroll
            for (int n = 0; n < G4; ++n)
#pragma unroll
                for (int st = 0; st < 2; ++st)
                    acur[n][st] = *(const bf16x8*)(
                        ag + ((size_t)(((kt + 1) * G4 + n) * 2 + st) * 64 + l) * 8);
            VMWAIT8()
        }
    }
#undef STAGE

    // Epilogue: h overlays sh.b (cross-wave) -> real barriers from here on.
    __syncthreads();
#pragma unroll
    for (int np2 = 0; np2 < 2; ++np2) {
#pragma unroll
        for (int nn = 0; nn < 2; ++nn) {
            const int n = np2 * 2 + nn;
#pragma unroll
            for (int st = 0; st < 2; ++st)
#pragma unroll
                for (int r = 0; r < 4; ++r) {
                    double hv = (double)acc[0][st][n][r]
                              + (double)acc[1][st][n][r]
                              + (double)acc[2][st][n][r];
                    sh.h[nn][st * 16 + lg * 4 + r][wv * 16 + lm] = hv;
                }
        }
        __syncthreads();
        if (t < 128) {
            const int nn = t >> 6;
            const int pl = t & 63;
            const int pp = chunk * CHUNK + pl;
            if (pp < NP) {
                double b2d = (double)B2[pp];
                double mem = 0.0, spk = 0.0;
                int cnt = 0;
#pragma unroll
                for (int s = 0; s < NS; ++s) {
                    double hh = sh.h[nn][s][pl] + b2d;
                    mem = 0.9 * mem + hh - spk;
                    bool sp = mem > 1.0;
                    spk = sp ? 1.0 : 0.0;
                    cnt += sp;
                }
                out[(size_t)(ng * G4 + np2 * 2 + nn) * OUTC + NFEAT + pp] =
                    (float)((double)cnt / 30.0);
            }
        }
        if (np2 == 0) __syncthreads();   // LIF readers done before rewrite
    }
}

// ---------------------------------------------------------------------------
// Tier B fallback (round-12 structure, GB=4, (256,2)): proven 260 us.
// ---------------------------------------------------------------------------
__global__ __launch_bounds__(256, 2) void sbls_k2_bf16(
    const unsigned short* __restrict__ slt,
    const float*    __restrict__ B2,
    const unsigned* __restrict__ colmask,
    float*          __restrict__ out)
{
    __shared__ unsigned smask[GB][NFEAT];
    union ShU {
        unsigned short afrag[32][64][8];
        double h[GB][32][67];
    };
    __shared__ __align__(16) ShU shu;

    const int ng    = blockIdx.x;
    const int chunk = blockIdx.y;
    const int t  = threadIdx.x;
    const int l  = t & 63;
    const int wv = t >> 6;
    const int lm = l & 15;
    const int lg = l >> 4;

    for (int i = t; i < GB * NFEAT; i += 256)
        smask[i / NFEAT][i % NFEAT] = colmask[(ng * GB + i / NFEAT) * NFEAT + (i % NFEAT)];
    __syncthreads();

    for (int e = t; e < 32 * 64; e += 256) {
        int fid = e >> 6, L = e & 63;
        int st = fid & 1, n = (fid >> 1) & 3, kt = fid >> 3;
        int lgE = L >> 4, lmE = L & 15;
        int s = st * 16 + lmE;
        bf16x8 v;
#pragma unroll
        for (int j = 0; j < 8; ++j) {
            int f = kt * 32 + lgE * 8 + j;
            unsigned mv = (f < NFEAT) ? smask[n][f] : 0u;
            v[j] = (short)(((mv >> s) & 1u) ? 0x3F80 : 0);
        }
        *(bf16x8*)(&shu.afrag[fid][L][0]) = v;
    }
    __syncthreads();

    const int p = chunk * CHUNK + wv * 16 + lm;
    const int prow = (p < NP) ? p : (NP - 1);
    const unsigned short* bbase = slt + (size_t)prow * 128 + lg * 8;

    f32x4 acc[3][2][GB];
#pragma unroll
    for (int wp = 0; wp < 3; ++wp)
#pragma unroll
        for (int st = 0; st < 2; ++st)
#pragma unroll
            for (int n = 0; n < GB; ++n)
                acc[wp][st][n] = (f32x4){0.f, 0.f, 0.f, 0.f};

    bf16x8 bcur[NWIN], bnxt[NWIN];
#pragma unroll
    for (int w = 0; w < NWIN; ++w)
        bcur[w] = *(const bf16x8*)(bbase + (size_t)w * NP * 128);

#pragma unroll
    for (int kt = 0; kt < 4; ++kt) {
        bf16x8 a[GB][2];
#pragma unroll
        for (int n = 0; n < GB; ++n)
#pragma unroll
            for (int st = 0; st < 2; ++st)
                a[n][st] = *(const bf16x8*)(&shu.afrag[(kt * GB + n) * 2 + st][l][0]);

        if (kt < 3) {
#pragma unroll
            for (int w = 0; w < NWIN; ++w)
                bnxt[w] = *(const bf16x8*)(bbase + (size_t)w * NP * 128 + (kt + 1) * 32);
        }

#pragma unroll
        for (int w = 0; w < NWIN; ++w)
#pragma unroll
            for (int n = 0; n < GB; ++n)
#pragma unroll
                for (int st = 0; st < 2; ++st)
                    acc[w >> 1][st][n] = __builtin_amdgcn_mfma_f32_16x16x32_bf16(
                        a[n][st], bcur[w], acc[w >> 1][st][n], 0, 0, 0);

        if (kt < 3) {
#pragma unroll
            for (int w = 0; w < NWIN; ++w) bcur[w] = bnxt[w];
        }
    }

    __syncthreads();
#pragma unroll
    for (int n = 0; n < GB; ++n)
#pragma unroll
        for (int st = 0; st < 2; ++st)
#pragma unroll
            for (int r = 0; r < 4; ++r) {
                double hv = (double)acc[0][st][n][r]
                          + (double)acc[1][st][n][r]
                          + (double)acc[2][st][n][r];
                shu.h[n][st * 16 + lg * 4 + r][wv * 16 + lm] = hv;
            }
    __syncthreads();
    {
        const int nn = t >> 6;
        const int pl = t & 63;
        const int pp = chunk * CHUNK + pl;
        if (pp < NP) {
            double b2d = (double)B2[pp];
            double mem = 0.0, spk = 0.0;
            int cnt = 0;
#pragma unroll
            for (int s = 0; s < NS; ++s) {
                double hh = shu.h[nn][s][pl] + b2d;
                mem = 0.9 * mem + hh - spk;
                bool sp = mem > 1.0;
                spk = sp ? 1.0 : 0.0;
                cnt += sp;
            }
            out[(size_t)(ng * GB + nn) * OUTC + NFEAT + pp] = (float)((double)cnt / 30.0);
        }
    }
}

// ---------------------------------------------------------------------------
// Tier C fallback (round-5 f64 MFMA, probed layout).
// ---------------------------------------------------------------------------
__global__ __launch_bounds__(256, 2) void sbls_k2_f64(
    const float*    __restrict__ W2, const float* __restrict__ B2,
    const unsigned* __restrict__ colmask, float* __restrict__ out)
{
    __shared__ unsigned smask[NFEAT];
    __shared__ double h_lds[32][130];

    const int n     = blockIdx.x;
    const int chunk = blockIdx.y;
    const int l  = threadIdx.x & 63;
    const int wv = threadIdx.x >> 6;
    const int lm = l & 15;
    const int lg = l >> 4;

    if (threadIdx.x < NFEAT)
        smask[threadIdx.x] = colmask[n * NFEAT + threadIdx.x];

    f64x4 zero = (f64x4){0.0, 0.0, 0.0, 0.0};
    f64x4 d1 = mfma_f64((double)lm, 1.0, zero);
    f64x4 d2 = mfma_f64(1.0, (double)lm, zero);
    int srow[4], pcol[4];
#pragma unroll
    for (int r = 0; r < 4; ++r) {
        int a = (int)(d1[r] * 0.25);
        int b = (int)(d2[r] * 0.25);
        srow[r] = (a < 0) ? 0 : (a > 15 ? 15 : a);
        pcol[r] = (b < 0) ? 0 : (b > 15 ? 15 : b);
    }
    __syncthreads();

    f64x4 acc[2][4];
    int pclamp[4];
#pragma unroll
    for (int i = 0; i < 4; ++i) {
        int p = chunk * 256 + (wv * 4 + i) * 16 + lm;
        pclamp[i] = (p < NP) ? p : (NP - 1);
        acc[0][i] = zero; acc[1][i] = zero;
    }
    for (int kt = 0; kt < 25; ++kt) {
        unsigned mw = smask[kt * 4 + lg];
        double a0 = ((mw >> lm) & 1u) ? 1.0 : 0.0;
        double a1 = ((mw >> (lm + 16)) & 1u) ? 1.0 : 0.0;
        const float* wrow = W2 + (size_t)(kt * 4 + lg) * NP;
#pragma unroll
        for (int i = 0; i < 4; ++i) {
            double b = (double)wrow[pclamp[i]];
            acc[0][i] = mfma_f64(a0, b, acc[0][i]);
            acc[1][i] = mfma_f64(a1, b, acc[1][i]);
        }
    }
#pragma unroll
    for (int hp = 0; hp < 2; ++hp) {
        __syncthreads();
        if ((wv >> 1) == hp) {
#pragma unroll
            for (int i = 0; i < 4; ++i) {
                int tloc = (wv & 1) * 4 + i;
#pragma unroll
                for (int st = 0; st < 2; ++st)
#pragma unroll
                    for (int r = 0; r < 4; ++r)
                        h_lds[st * 16 + srow[r]][tloc * 16 + pcol[r]] = acc[st][i][r];
            }
        }
        __syncthreads();
        if (threadIdx.x < 128) {
            int p = chunk * 256 + hp * 128 + threadIdx.x;
            if (p < NP) {
                double b2d = (double)B2[p];
                double mem = 0.0, spk = 0.0;
                int cnt = 0;
#pragma unroll
                for (int s = 0; s < NS; ++s) {
                    double hh = h_lds[s][threadIdx.x] + b2d;
                    mem = 0.9 * mem + hh - spk;
                    bool sp = mem > 1.0;
                    spk = sp ? 1.0 : 0.0;
                    cnt += sp;
                }
                out[(size_t)n * OUTC + NFEAT + p] = (float)((double)cnt / 30.0);
            }
        }
    }
}

// ---------------------------------------------------------------------------
extern "C" void kernel_launch(void* const* d_in, const int* in_sizes, int n_in,
                              void* d_out, int out_size, void* d_ws, size_t ws_size,
                              hipStream_t stream) {
    const float* X  = (const float*)d_in[0];
    const float* W1 = (const float*)d_in[1];
    const float* B1 = (const float*)d_in[2];
    const float* W2 = (const float*)d_in[3];
    const float* B2 = (const float*)d_in[4];
    const float* U  = (const float*)d_in[5];
    float* out = (float*)d_out;

    unsigned* colmask = (unsigned*)d_ws;                      // 819,200 B
    const size_t SLT_OFF   = 1u << 20;                        // 1 MiB
    const size_t SLT_BYTES = (size_t)NWIN * NP * 128 * 2;     // 2,560,000 B
    const size_t AF_OFF    = 4u << 20;                        // 4 MiB
    const size_t AF_BYTES  = (size_t)(NN / G4) * 32 * 64 * 8 * 2; // 16,777,216 B
    unsigned short* slt    = (unsigned short*)((char*)d_ws + SLT_OFF);
    unsigned short* afragG = (unsigned short*)((char*)d_ws + AF_OFF);
    bool tierA = (ws_size >= AF_OFF + AF_BYTES);
    bool tierB = (ws_size >= SLT_OFF + SLT_BYTES);

    sbls_k1<<<NN / K1B, 256, 0, stream>>>(X, W1, B1, U, out, colmask);

    if (tierA) {
        sbls_aux<<<1000 + NN / G4, 256, 0, stream>>>(W2, slt, colmask, afragG);
        dim3 grid(512, 32);                                   // remapped in-kernel
        sbls_k2_ga<<<grid, 256, 0, stream>>>(slt, afragG, B2, out);
    } else if (tierB) {
        sbls_slice<<<(NP * 128 + 255) / 256, 256, 0, stream>>>(W2, slt);
        dim3 grid(NN / GB, (NP + CHUNK - 1) / CHUNK);
        sbls_k2_bf16<<<grid, 256, 0, stream>>>(slt, B2, colmask, out);
    } else {
        dim3 grid(NN, (NP + 255) / 256);
        sbls_k2_f64<<<grid, 256, 0, stream>>>(W2, B2, colmask, out);
    }
}